// Round 8
// baseline (6794.326 us; speedup 1.0000x reference)
//
#include <hip/hip_runtime.h>
#include <math.h>

#define NB 32      // batch
#define NT 12      // time steps
#define NN 307     // nodes
#define NE 10      // embedding dim
#define NH 64      // hidden
#define NCIN 65    // 1 + H
#define NO2 128    // 2H
#define BG 16      // batches per einsum block

__device__ __forceinline__ float sigmoidf_(float x) {
    return 1.0f / (1.0f + __expf(-x));
}

// ---------------- precompute ----------------

__global__ void mg_ne0(const float* __restrict__ src,
                       const float* __restrict__ node_emb,
                       const float* __restrict__ tid_emb,
                       const float* __restrict__ dow_emb,
                       const float* __restrict__ hol_emb,
                       const float* __restrict__ hop_w,
                       const float* __restrict__ hop_b,
                       float* __restrict__ ne0)
{
    int idx = blockIdx.x * blockDim.x + threadIdx.x;
    const int total = NB * NT * NN;
    if (idx >= total) return;
    int n = idx % NN;
    const float* s = src + (size_t)idx * 5;
    int ti = (int)(s[1] * 288.0f); ti = ti < 0 ? 0 : (ti > 287 ? 287 : ti);
    int dw = (int)s[2];            dw = dw < 0 ? 0 : (dw > 6 ? 6 : dw);
    int hl = (int)s[3];            hl = hl < 0 ? 0 : (hl > 1 ? 1 : hl);
    float hop = s[4];
    float* o = ne0 + (size_t)idx * NE;
    #pragma unroll
    for (int e = 0; e < NE; ++e) {
        float v = node_emb[n*NE+e] * tid_emb[ti*NE+e] * dow_emb[dw*NE+e] * hol_emb[hl*NE+e];
        o[e] = v * (hop * hop_w[e] + hop_b[e]);
    }
}

__global__ void mg_weff(const float* __restrict__ node_emb,
                        const float* __restrict__ gw, const float* __restrict__ gb,
                        const float* __restrict__ uw, const float* __restrict__ ub,
                        float* __restrict__ weff_g, float* __restrict__ beff_g,
                        float* __restrict__ weff_u, float* __restrict__ beff_u)
{
    const int NG  = 3*NN*2*NCIN*NO2;
    const int NU  = 3*NN*2*NCIN*NH;
    const int NBG = 3*NN*NO2;
    const int NBU = 3*NN*NH;
    int total = NG + NU + NBG + NBU;
    for (int idx = blockIdx.x*blockDim.x + threadIdx.x; idx < total;
         idx += gridDim.x*blockDim.x) {
        if (idx < NG) {
            int j = idx;
            int o = j & (NO2-1); j >>= 7;
            int i = j % NCIN;    j /= NCIN;
            int k = j & 1;       j >>= 1;
            int n = j % NN;      int c = j / NN;
            float a = 0.f;
            #pragma unroll
            for (int e = 0; e < NE; ++e)
                a += node_emb[n*NE+e] * gw[(((c*NE+e)*2+k)*NCIN+i)*NO2 + o];
            weff_g[idx] = a;
        } else if (idx < NG + NU) {
            int j = idx - NG; int jo = j;
            int o = j & (NH-1); j >>= 6;
            int i = j % NCIN;   j /= NCIN;
            int k = j & 1;      j >>= 1;
            int n = j % NN;     int c = j / NN;
            float a = 0.f;
            #pragma unroll
            for (int e = 0; e < NE; ++e)
                a += node_emb[n*NE+e] * uw[(((c*NE+e)*2+k)*NCIN+i)*NH + o];
            weff_u[jo] = a;
        } else if (idx < NG + NU + NBG) {
            int j = idx - NG - NU;
            int o = j & (NO2-1);
            int n = (j >> 7) % NN; int c = (j >> 7) / NN;
            float a = 0.f;
            #pragma unroll
            for (int e = 0; e < NE; ++e)
                a += node_emb[n*NE+e] * gb[(c*NE+e)*NO2 + o];
            beff_g[j] = a;
        } else {
            int j = idx - NG - NU - NBG;
            int o = j & (NH-1);
            int n = (j >> 6) % NN; int c = (j >> 6) / NN;
            float a = 0.f;
            #pragma unroll
            for (int e = 0; e < NE; ++e)
                a += node_emb[n*NE+e] * ub[(c*NE+e)*NH + o];
            beff_u[j] = a;
        }
    }
}

__global__ void mg_zero(float* __restrict__ p, int count) {
    int idx = blockIdx.x * blockDim.x + threadIdx.x;
    if (idx < count) p[idx] = 0.0f;
}

// ---------------- per-cell kernels ----------------

// AB (fused): one block per batch. Build cat=[x,state]; small MLP -> nv for all
// nodes; row-sums of relu(nv nv^T) -> dd.  g never materialized.
__global__ __launch_bounds__(256) void mg_ab(
    const float* __restrict__ state,
    const float* __restrict__ xptr, int xbs, int xns,
    const float* __restrict__ ne0t,
    const float* __restrict__ w1, const float* __restrict__ b1,
    const float* __restrict__ w2, const float* __restrict__ b2,
    const float* __restrict__ w3, const float* __restrict__ b3,
    float* __restrict__ cat, float* __restrict__ nvout, float* __restrict__ dd)
{
    int b = blockIdx.x;
    int t = threadIdx.x;
    __shared__ float scat[NN][NCIN];   // ~80 KB
    __shared__ float snv[NN][11];      // pad 10->11 (bank spread), ~13.5 KB
    for (int idx = t; idx < NN*NCIN; idx += 256) {
        int n = idx / NCIN, i = idx - n*NCIN;
        float v = (i == 0) ? xptr[(size_t)b*xbs + (size_t)n*xns]
                           : state[((size_t)b*NN + n)*NH + (i-1)];
        scat[n][i] = v;
        cat[((size_t)b*NN + n)*NCIN + i] = v;
    }
    __syncthreads();
    for (int n = t; n < NN; n += 256) {
        float h1[16];
        #pragma unroll
        for (int j = 0; j < 16; ++j) {
            float a = b1[j];
            const float* w = w1 + j*NCIN;
            for (int i = 0; i < NCIN; ++i) a += scat[n][i] * w[i];
            h1[j] = sigmoidf_(a);
        }
        float h2[2];
        #pragma unroll
        for (int j = 0; j < 2; ++j) {
            float a = b2[j];
            const float* w = w2 + j*16;
            #pragma unroll
            for (int i = 0; i < 16; ++i) a += h1[i] * w[i];
            h2[j] = sigmoidf_(a);
        }
        #pragma unroll
        for (int e = 0; e < NE; ++e) {
            float xe = h2[0]*w3[e*2] + h2[1]*w3[e*2+1] + b3[e];
            float nvv = tanhf(ne0t[(size_t)b*NT*NN*NE + n*NE + e] * xe);
            snv[n][e] = nvv;
            nvout[((size_t)b*NN + n)*NE + e] = nvv;
        }
    }
    __syncthreads();
    for (int n = t; n < NN; n += 256) {
        float v0=snv[n][0],v1=snv[n][1],v2=snv[n][2],v3=snv[n][3],v4=snv[n][4],
              v5=snv[n][5],v6=snv[n][6],v7=snv[n][7],v8=snv[n][8],v9=snv[n][9];
        float sum = 0.0f;
        for (int m = 0; m < NN; ++m) {
            float dot = v0*snv[m][0]+v1*snv[m][1]+v2*snv[m][2]+v3*snv[m][3]
                      + v4*snv[m][4]+v5*snv[m][5]+v6*snv[m][6]+v7*snv[m][7]
                      + v8*snv[m][8]+v9*snv[m][9];
            sum += fmaxf(dot, 0.0f);
        }
        dd[b*NN + n] = 1.0f / sqrtf(sum);
    }
}

// B2: dd only, from nv (for the 2nd GCN whose nv comes from mg_d1)
__global__ __launch_bounds__(256) void mg_b2(
    const float* __restrict__ nv, float* __restrict__ dd)
{
    int b = blockIdx.x;
    int t = threadIdx.x;
    __shared__ float snv[NN][11];
    for (int idx = t; idx < NN*NE; idx += 256) {
        int n = idx / NE, e = idx - n*NE;
        snv[n][e] = nv[(size_t)b*NN*NE + idx];
    }
    __syncthreads();
    for (int n = t; n < NN; n += 256) {
        float v0=snv[n][0],v1=snv[n][1],v2=snv[n][2],v3=snv[n][3],v4=snv[n][4],
              v5=snv[n][5],v6=snv[n][6],v7=snv[n][7],v8=snv[n][8],v9=snv[n][9];
        float sum = 0.0f;
        for (int m = 0; m < NN; ++m) {
            float dot = v0*snv[m][0]+v1*snv[m][1]+v2*snv[m][2]+v3*snv[m][3]
                      + v4*snv[m][4]+v5*snv[m][5]+v6*snv[m][6]+v7*snv[m][7]
                      + v8*snv[m][8]+v9*snv[m][9];
            sum += fmaxf(dot, 0.0f);
        }
        dd[b*NN + n] = 1.0f / sqrtf(sum);
    }
}

// C2: Lx[b,n,i] = d[n] * sum_m relu(nv_n.nv_m)*d[m]*cat[m,i]
// g-tile recomputed in LDS from nv (rank-10), never touches HBM.
#define GR 16
__global__ __launch_bounds__(256) void mg_c2(
    const float* __restrict__ nv, const float* __restrict__ dd,
    const float* __restrict__ cat, float* __restrict__ lx)
{
    int blk = blockIdx.x;
    int b = blk / 20;
    int n0 = (blk % 20) * GR;
    int t = threadIdx.x;
    int j = t >> 4;
    int i0 = t & 15;
    __shared__ float catc[64][66];     // 16.9 KB
    __shared__ float snv[NN][11];      // 13.5 KB
    __shared__ float dcf[NN];          // 1.2 KB
    __shared__ float gj[GR][64];       // 4 KB (d[m] folded in)
    for (int idx = t; idx < NN*NE; idx += 256) {
        int n = idx / NE, e = idx - n*NE;
        snv[n][e] = nv[(size_t)b*NN*NE + idx];
    }
    for (int idx = t; idx < NN; idx += 256) dcf[idx] = dd[b*NN + idx];
    __syncthreads();
    float acc0=0.f, acc1=0.f, acc2=0.f, acc3=0.f, acc4=0.f;
    for (int m0 = 0; m0 < NN; m0 += 64) {
        for (int idx = t; idx < 64*65; idx += 256) {
            int ml = idx / 65, ii = idx % 65;
            int m = m0 + ml;
            catc[ml][ii] = (m < NN) ? cat[((size_t)b*NN + m)*NCIN + ii] : 0.f;
        }
        for (int idx = t; idx < GR*64; idx += 256) {
            int jj = idx >> 6, ml = idx & 63;
            int row = n0 + jj, m = m0 + ml;
            float gv = 0.f;
            if (row < NN && m < NN) {
                float dot = snv[row][0]*snv[m][0]+snv[row][1]*snv[m][1]
                          + snv[row][2]*snv[m][2]+snv[row][3]*snv[m][3]
                          + snv[row][4]*snv[m][4]+snv[row][5]*snv[m][5]
                          + snv[row][6]*snv[m][6]+snv[row][7]*snv[m][7]
                          + snv[row][8]*snv[m][8]+snv[row][9]*snv[m][9];
                gv = fmaxf(dot, 0.0f) * dcf[m];
            }
            gj[jj][ml] = gv;
        }
        __syncthreads();
        #pragma unroll 4
        for (int ml = 0; ml < 64; ++ml) {
            float coef = gj[j][ml];
            acc0 += coef * catc[ml][i0];
            acc1 += coef * catc[ml][i0+16];
            acc2 += coef * catc[ml][i0+32];
            acc3 += coef * catc[ml][i0+48];
            acc4 += coef * catc[ml][64];
        }
        __syncthreads();
    }
    int row = n0 + j;
    if (row < NN) {
        float dn = dcf[row];
        size_t base = ((size_t)b*NN + row)*NCIN;
        lx[base + i0]      = dn*acc0;
        lx[base + i0+16]   = dn*acc1;
        lx[base + i0+32]   = dn*acc2;
        lx[base + i0+48]   = dn*acc3;
        if (i0 == 0) lx[base + 64] = dn*acc4;
    }
}

// D1: gates einsum -> zr=sigmoid(.); fused cand = [x, z*state] and MLP_u -> nv
__global__ __launch_bounds__(256) void mg_d1(
    const float* __restrict__ cat1, const float* __restrict__ lxb,
    const float* __restrict__ weff, const float* __restrict__ beff,
    const float* __restrict__ state,
    const float* __restrict__ xptr, int xbs, int xns,
    const float* __restrict__ ne0t,
    const float* __restrict__ u1w, const float* __restrict__ u1b,
    const float* __restrict__ u2w, const float* __restrict__ u2b,
    const float* __restrict__ u3w, const float* __restrict__ u3b,
    float* __restrict__ zr, float* __restrict__ cat2, float* __restrict__ nvout)
{
    int n = blockIdx.x >> 1;
    int b0 = (blockIdx.x & 1) * BG;
    int t = threadIdx.x;
    __shared__ float sin_[130][20];   // [i][b-local], padded stride 20 (16B-aligned rows)
    __shared__ float szr[BG][NO2];
    __shared__ float scand[BG][NCIN];
    __shared__ float sh1[BG][16];
    __shared__ float sh2[BG][2];
    for (int idx = t; idx < 130*BG; idx += 256) {
        int i = idx % 130, bb = idx / 130;
        int b = b0 + bb;
        float v = (i < NCIN) ? cat1[((size_t)b*NN+n)*NCIN + i]
                             : lxb[((size_t)b*NN+n)*NCIN + (i-NCIN)];
        sin_[i][bb] = v;
    }
    __syncthreads();
    int o = t & (NO2-1);
    int bs = t >> 7;   // 0..1 -> 8 batches each
    float acc[8];
    float bv = beff[n*NO2 + o];
    #pragma unroll
    for (int u = 0; u < 8; ++u) acc[u] = bv;
    const float* w0 = weff + (size_t)n * 2*NCIN*NO2;
    for (int i = 0; i < 130; ++i) {
        float w = w0[i*NO2 + o];
        const float4* s4 = (const float4*)&sin_[i][bs*8];
        float4 a = s4[0], c = s4[1];
        acc[0] += a.x*w; acc[1] += a.y*w; acc[2] += a.z*w; acc[3] += a.w*w;
        acc[4] += c.x*w; acc[5] += c.y*w; acc[6] += c.z*w; acc[7] += c.w*w;
    }
    #pragma unroll
    for (int u = 0; u < 8; ++u) {
        int bb = bs*8 + u;
        float zv = sigmoidf_(acc[u]);
        zr[((size_t)(b0+bb)*NN+n)*NO2 + o] = zv;
        szr[bb][o] = zv;
    }
    __syncthreads();
    for (int idx = t; idx < BG*NCIN; idx += 256) {
        int bb = idx / NCIN, i = idx % NCIN;
        int b = b0 + bb;
        float v;
        if (i == 0) v = xptr[(size_t)b*xbs + (size_t)n*xns];
        else        v = szr[bb][i-1] * state[((size_t)b*NN+n)*NH + (i-1)];
        scand[bb][i] = v;
        cat2[((size_t)b*NN+n)*NCIN + i] = v;
    }
    __syncthreads();
    {
        int bb = t >> 4, j = t & 15;
        float a = u1b[j];
        const float* w = u1w + j*NCIN;
        #pragma unroll
        for (int i = 0; i < NCIN; ++i) a += scand[bb][i] * w[i];
        sh1[bb][j] = sigmoidf_(a);
    }
    __syncthreads();
    if (t < BG*2) {
        int bb = t >> 1, j = t & 1;
        float a = u2b[j];
        const float* w = u2w + j*16;
        #pragma unroll
        for (int i = 0; i < 16; ++i) a += sh1[bb][i] * w[i];
        sh2[bb][j] = sigmoidf_(a);
    }
    __syncthreads();
    if (t < BG*NE) {
        int bb = t / NE, e = t % NE;
        int b = b0 + bb;
        float xe = sh2[bb][0]*u3w[e*2] + sh2[bb][1]*u3w[e*2+1] + u3b[e];
        nvout[((size_t)b*NN+n)*NE + e] =
            tanhf(ne0t[(size_t)b*NT*NN*NE + n*NE + e] * xe);
    }
}

// D2: candidate einsum -> hc=tanh(.); GRU update h = r*state + (1-r)*hc
__global__ __launch_bounds__(256) void mg_d2(
    const float* __restrict__ cat2, const float* __restrict__ lxb,
    const float* __restrict__ weff, const float* __restrict__ beff,
    const float* __restrict__ zr,
    float* __restrict__ state, float* __restrict__ outi)
{
    int n = blockIdx.x >> 1;
    int b0 = (blockIdx.x & 1) * BG;
    int t = threadIdx.x;
    __shared__ float sin_[130][20];
    for (int idx = t; idx < 130*BG; idx += 256) {
        int i = idx % 130, bb = idx / 130;
        int b = b0 + bb;
        float v = (i < NCIN) ? cat2[((size_t)b*NN+n)*NCIN + i]
                             : lxb[((size_t)b*NN+n)*NCIN + (i-NCIN)];
        sin_[i][bb] = v;
    }
    __syncthreads();
    int o = t & (NH-1);
    int bs = t >> 6;   // 0..3 -> 4 batches each
    float acc[4];
    float bv = beff[n*NH + o];
    #pragma unroll
    for (int u = 0; u < 4; ++u) acc[u] = bv;
    const float* w0 = weff + (size_t)n * 2*NCIN*NH;
    for (int i = 0; i < 130; ++i) {
        float w = w0[i*NH + o];
        const float4* s4 = (const float4*)&sin_[i][bs*4];
        float4 a = s4[0];
        acc[0] += a.x*w; acc[1] += a.y*w; acc[2] += a.z*w; acc[3] += a.w*w;
    }
    #pragma unroll
    for (int u = 0; u < 4; ++u) {
        int b = b0 + bs*4 + u;
        float hc = tanhf(acc[u]);
        size_t sb = ((size_t)b*NN+n)*NH + o;
        float st = state[sb];
        float r = zr[((size_t)b*NN+n)*NO2 + NH + o];
        float h = r*st + (1.0f - r)*hc;
        state[sb] = h;
        if (outi) outi[(size_t)b*2*NN*NH + (size_t)n*NH + o] = h;
    }
}

// skip conv between layers: x2 = conv(out1) + flow
__global__ void mg_conv(
    const float* __restrict__ out1, const float* __restrict__ skip_w,
    const float* __restrict__ skip_b, const float* __restrict__ src,
    float* __restrict__ x2)
{
    int idx = blockIdx.x*blockDim.x + threadIdx.x;
    if (idx >= NB*NT*NN) return;
    int n = idx % NN; int r = idx / NN; int o = r % NT; int b = r / NT;
    float acc = skip_b[o];
    #pragma unroll
    for (int c = 0; c < 2; ++c) {
        const float* p = out1 + ((size_t)(b*2+c)*NN + n)*NH;
        const float* w = skip_w + (o*2+c)*NH;
        #pragma unroll
        for (int k = 0; k < NH; ++k) acc += p[k]*w[k];
    }
    x2[idx] = acc + src[(size_t)idx*5];
}

// layernorm over concat(out1,out2) + end conv -> output
__global__ __launch_bounds__(128) void mg_final(
    const float* __restrict__ out1, const float* __restrict__ out2,
    const float* __restrict__ ln_g, const float* __restrict__ ln_b,
    const float* __restrict__ end_w, const float* __restrict__ end_b,
    float* __restrict__ dout)
{
    int bn = blockIdx.x;
    int b = bn / NN, n = bn % NN;
    int t = threadIdx.x;
    __shared__ float snorm[2][NO2];
    __shared__ float red[2];
    for (int c = 0; c < 2; ++c) {
        size_t base = ((size_t)(b*2+c)*NN + n)*NH;
        float p = (t < NH) ? out1[base + t] : out2[base + (t - NH)];
        float s = p;
        #pragma unroll
        for (int off = 32; off > 0; off >>= 1) s += __shfl_down(s, off, 64);
        if ((t & 63) == 0) red[t >> 6] = s;
        __syncthreads();
        float m = (red[0] + red[1]) * (1.0f/128.0f);
        __syncthreads();
        float df = p - m;
        float s2 = df*df;
        #pragma unroll
        for (int off = 32; off > 0; off >>= 1) s2 += __shfl_down(s2, off, 64);
        if ((t & 63) == 0) red[t >> 6] = s2;
        __syncthreads();
        float v = (red[0] + red[1]) * (1.0f/128.0f);
        snorm[c][t] = df / sqrtf(v + 1e-12f) * ln_g[t] + ln_b[t];
        __syncthreads();
    }
    if (t < NT) {
        float a = end_b[t];
        const float* w = end_w + t*2*NO2;
        for (int c = 0; c < 2; ++c)
            for (int j = 0; j < NO2; ++j)
                a += snorm[c][j] * w[c*NO2 + j];
        dout[(size_t)(b*NT + t)*NN + n] = a;
    }
}

// ---------------- host ----------------

extern "C" void kernel_launch(void* const* d_in, const int* in_sizes, int n_in,
                              void* d_out, int out_size, void* d_ws, size_t ws_size,
                              hipStream_t stream)
{
    const float* src      = (const float*)d_in[0];
    const float* node_emb = (const float*)d_in[1];
    const float* tid_emb  = (const float*)d_in[2];
    const float* dow_emb  = (const float*)d_in[3];
    const float* hol_emb  = (const float*)d_in[4];
    const float* hop_w    = (const float*)d_in[5];
    const float* hop_b    = (const float*)d_in[6];
    const float* gw  = (const float*)d_in[7];
    const float* gb  = (const float*)d_in[8];
    const float* g1w = (const float*)d_in[9];
    const float* g1b = (const float*)d_in[10];
    const float* g2w = (const float*)d_in[11];
    const float* g2b = (const float*)d_in[12];
    const float* g3w = (const float*)d_in[13];
    const float* g3b = (const float*)d_in[14];
    const float* uw  = (const float*)d_in[15];
    const float* ub  = (const float*)d_in[16];
    const float* u1w = (const float*)d_in[17];
    const float* u1b = (const float*)d_in[18];
    const float* u2w = (const float*)d_in[19];
    const float* u2b = (const float*)d_in[20];
    const float* u3w = (const float*)d_in[21];
    const float* u3b = (const float*)d_in[22];
    const float* skip_w = (const float*)d_in[23];
    const float* skip_b = (const float*)d_in[24];
    const float* ln_g = (const float*)d_in[25];
    const float* ln_b = (const float*)d_in[26];
    const float* end_w = (const float*)d_in[27];
    const float* end_b = (const float*)d_in[28];
    float* dout = (float*)d_out;

    float* ws = (float*)d_ws;
    size_t off = 0;
    float* weff_g = ws + off; off += (size_t)3*NN*2*NCIN*NO2;  // 15.3M
    float* weff_u = ws + off; off += (size_t)3*NN*2*NCIN*NH;   // 7.7M
    float* beff_g = ws + off; off += (size_t)3*NN*NO2;
    float* beff_u = ws + off; off += (size_t)3*NN*NH;
    float* ne0    = ws + off; off += (size_t)NB*NT*NN*NE;
    float* st     = ws + off; off += (size_t)2*NB*NN*NH;
    float* cat1   = ws + off; off += (size_t)NB*NN*NCIN;
    float* cat2   = ws + off; off += (size_t)NB*NN*NCIN;
    float* nv     = ws + off; off += (size_t)NB*NN*NE;
    float* dd     = ws + off; off += (size_t)NB*NN;
    float* lx     = ws + off; off += (size_t)NB*NN*NCIN;
    float* zr     = ws + off; off += (size_t)NB*NN*NO2;
    float* out1   = ws + off; off += (size_t)NB*2*NN*NH;
    float* out2   = ws + off; off += (size_t)NB*2*NN*NH;
    float* x2     = ws + off; off += (size_t)NB*NT*NN;

    mg_ne0<<<(NB*NT*NN + 255)/256, 256, 0, stream>>>(
        src, node_emb, tid_emb, dow_emb, hol_emb, hop_w, hop_b, ne0);
    mg_weff<<<4096, 256, 0, stream>>>(
        node_emb, gw, gb, uw, ub, weff_g, beff_g, weff_u, beff_u);

    const int stcount = 2*NB*NN*NH;
    mg_zero<<<(stcount+255)/256, 256, 0, stream>>>(st, stcount);

    auto cell = [&](int c, int t, const float* xptr, int xbs, int xns,
                    float* state, float* outi) {
        const float* ne0t = ne0 + (size_t)t*NN*NE;
        mg_ab<<<NB, 256, 0, stream>>>(state, xptr, xbs, xns, ne0t,
            g1w + c*16*NCIN, g1b + c*16, g2w + c*2*16, g2b + c*2,
            g3w + c*NE*2, g3b + c*NE, cat1, nv, dd);
        mg_c2<<<NB*20, 256, 0, stream>>>(nv, dd, cat1, lx);
        mg_d1<<<NN*(NB/BG), 256, 0, stream>>>(cat1, lx,
            weff_g + (size_t)c*NN*2*NCIN*NO2, beff_g + (size_t)c*NN*NO2,
            state, xptr, xbs, xns, ne0t,
            u1w + c*16*NCIN, u1b + c*16, u2w + c*2*16, u2b + c*2,
            u3w + c*NE*2, u3b + c*NE, zr, cat2, nv);
        mg_b2<<<NB, 256, 0, stream>>>(nv, dd);
        mg_c2<<<NB*20, 256, 0, stream>>>(nv, dd, cat2, lx);
        mg_d2<<<NN*(NB/BG), 256, 0, stream>>>(cat2, lx,
            weff_u + (size_t)c*NN*2*NCIN*NH, beff_u + (size_t)c*NN*NH,
            zr, state, outi);
    };

    // layer 1 (cell 0, single state chain)
    for (int t = 0; t < NT; ++t) {
        float* outi = (t >= NT-2) ? (out1 + (size_t)(t-(NT-2))*NN*NH) : nullptr;
        cell(0, t, src + (size_t)t*NN*5, NT*NN*5, 5, st, outi);
    }
    mg_conv<<<(NB*NT*NN+255)/256, 256, 0, stream>>>(out1, skip_w, skip_b, src, x2);
    mg_zero<<<(stcount+255)/256, 256, 0, stream>>>(st, stcount);
    // layer 2 (cells 1,2 alternating, two state chains)
    for (int t = 0; t < NT; ++t) {
        int c = 1 + (t & 1);
        float* state = st + (size_t)(t & 1)*NB*NN*NH;
        float* outi = (t >= NT-2) ? (out2 + (size_t)(t-(NT-2))*NN*NH) : nullptr;
        cell(c, t, x2 + (size_t)t*NN, NT*NN, 1, state, outi);
    }
    mg_final<<<NB*NN, 128, 0, stream>>>(out1, out2, ln_g, ln_b, end_w, end_b, dout);
}

// Round 11
// 4277.990 us; speedup vs baseline: 1.5882x; 1.5882x over previous
//
#include <hip/hip_runtime.h>
#include <math.h>

#define NB 32      // batch
#define NT 12      // time steps
#define NN 307     // nodes
#define NE 10      // embedding dim
#define NH 64      // hidden
#define NCIN 65    // 1 + H
#define NO2 128    // 2H
#define BG 16      // batches per einsum block

__device__ __forceinline__ float sigmoidf_(float x) {
    return 1.0f / (1.0f + __expf(-x));
}

// ---------------- precompute ----------------

__global__ void mg_ne0(const float* __restrict__ src,
                       const float* __restrict__ node_emb,
                       const float* __restrict__ tid_emb,
                       const float* __restrict__ dow_emb,
                       const float* __restrict__ hol_emb,
                       const float* __restrict__ hop_w,
                       const float* __restrict__ hop_b,
                       float* __restrict__ ne0)
{
    int idx = blockIdx.x * blockDim.x + threadIdx.x;
    const int total = NB * NT * NN;
    if (idx >= total) return;
    int n = idx % NN;
    const float* s = src + (size_t)idx * 5;
    int ti = (int)(s[1] * 288.0f); ti = ti < 0 ? 0 : (ti > 287 ? 287 : ti);
    int dw = (int)s[2];            dw = dw < 0 ? 0 : (dw > 6 ? 6 : dw);
    int hl = (int)s[3];            hl = hl < 0 ? 0 : (hl > 1 ? 1 : hl);
    float hop = s[4];
    float* o = ne0 + (size_t)idx * NE;
    #pragma unroll
    for (int e = 0; e < NE; ++e) {
        float v = node_emb[n*NE+e] * tid_emb[ti*NE+e] * dow_emb[dw*NE+e] * hol_emb[hl*NE+e];
        o[e] = v * (hop * hop_w[e] + hop_b[e]);
    }
}

__global__ void mg_weff(const float* __restrict__ node_emb,
                        const float* __restrict__ gw, const float* __restrict__ gb,
                        const float* __restrict__ uw, const float* __restrict__ ub,
                        float* __restrict__ weff_g, float* __restrict__ beff_g,
                        float* __restrict__ weff_u, float* __restrict__ beff_u)
{
    const int NG  = 3*NN*2*NCIN*NO2;
    const int NU  = 3*NN*2*NCIN*NH;
    const int NBG = 3*NN*NO2;
    const int NBU = 3*NN*NH;
    int total = NG + NU + NBG + NBU;
    for (int idx = blockIdx.x*blockDim.x + threadIdx.x; idx < total;
         idx += gridDim.x*blockDim.x) {
        if (idx < NG) {
            int j = idx;
            int o = j & (NO2-1); j >>= 7;
            int i = j % NCIN;    j /= NCIN;
            int k = j & 1;       j >>= 1;
            int n = j % NN;      int c = j / NN;
            float a = 0.f;
            #pragma unroll
            for (int e = 0; e < NE; ++e)
                a += node_emb[n*NE+e] * gw[(((c*NE+e)*2+k)*NCIN+i)*NO2 + o];
            weff_g[idx] = a;
        } else if (idx < NG + NU) {
            int j = idx - NG; int jo = j;
            int o = j & (NH-1); j >>= 6;
            int i = j % NCIN;   j /= NCIN;
            int k = j & 1;      j >>= 1;
            int n = j % NN;     int c = j / NN;
            float a = 0.f;
            #pragma unroll
            for (int e = 0; e < NE; ++e)
                a += node_emb[n*NE+e] * uw[(((c*NE+e)*2+k)*NCIN+i)*NH + o];
            weff_u[jo] = a;
        } else if (idx < NG + NU + NBG) {
            int j = idx - NG - NU;
            int o = j & (NO2-1);
            int n = (j >> 7) % NN; int c = (j >> 7) / NN;
            float a = 0.f;
            #pragma unroll
            for (int e = 0; e < NE; ++e)
                a += node_emb[n*NE+e] * gb[(c*NE+e)*NO2 + o];
            beff_g[j] = a;
        } else {
            int j = idx - NG - NU - NBG;
            int o = j & (NH-1);
            int n = (j >> 6) % NN; int c = (j >> 6) / NN;
            float a = 0.f;
            #pragma unroll
            for (int e = 0; e < NE; ++e)
                a += node_emb[n*NE+e] * ub[(c*NE+e)*NH + o];
            beff_u[j] = a;
        }
    }
}

__global__ void mg_zero(float* __restrict__ p, int count) {
    int idx = blockIdx.x * blockDim.x + threadIdx.x;
    if (idx < count) p[idx] = 0.0f;
}

// ---------------- per-cell kernels (round-6 validated bodies) ----------------

// A: build cat = [x, state], run small MLP -> nv  (only t=0 of each layer)
__global__ __launch_bounds__(64) void mg_a(
    const float* __restrict__ state,
    const float* __restrict__ xptr, int xbs, int xns,
    const float* __restrict__ ne0t,
    const float* __restrict__ w1, const float* __restrict__ b1,
    const float* __restrict__ w2, const float* __restrict__ b2,
    const float* __restrict__ w3, const float* __restrict__ b3,
    float* __restrict__ cat, float* __restrict__ nvout)
{
    int bn = blockIdx.x;
    int b = bn / NN, n = bn % NN;
    int t = threadIdx.x;
    __shared__ float sc[NCIN];
    __shared__ float sh1[16];
    __shared__ float sh2[2];
    float st = state[(size_t)bn*NH + t];
    sc[1+t] = st;
    cat[(size_t)bn*NCIN + 1 + t] = st;
    if (t == 0) {
        float xv = xptr[(size_t)b*xbs + (size_t)n*xns];
        sc[0] = xv;
        cat[(size_t)bn*NCIN] = xv;
    }
    __syncthreads();
    if (t < 16) {
        float a = b1[t];
        const float* w = w1 + t*NCIN;
        #pragma unroll
        for (int i = 0; i < NCIN; ++i) a += sc[i] * w[i];
        sh1[t] = sigmoidf_(a);
    }
    __syncthreads();
    if (t < 2) {
        float a = b2[t];
        const float* w = w2 + t*16;
        #pragma unroll
        for (int i = 0; i < 16; ++i) a += sh1[i] * w[i];
        sh2[t] = sigmoidf_(a);
    }
    __syncthreads();
    if (t < NE) {
        float xe = sh2[0]*w3[t*2] + sh2[1]*w3[t*2+1] + b3[t];
        nvout[(size_t)bn*NE + t] =
            tanhf(ne0t[(size_t)b*NT*NN*NE + n*NE + t] * xe);
    }
}

// B: g row + d
__global__ __launch_bounds__(64) void mg_b(
    const float* __restrict__ nv, float* __restrict__ g, float* __restrict__ dd)
{
    int bn = blockIdx.x;
    int b = bn / NN;
    int t = threadIdx.x;
    __shared__ float snv[NE];
    if (t < NE) snv[t] = nv[(size_t)bn*NE + t];
    __syncthreads();
    float v0=snv[0],v1=snv[1],v2=snv[2],v3=snv[3],v4=snv[4],
          v5=snv[5],v6=snv[6],v7=snv[7],v8=snv[8],v9=snv[9];
    float sum = 0.0f;
    for (int m = t; m < NN; m += 64) {
        const float* q = nv + ((size_t)b*NN + m)*NE;
        float dot = v0*q[0]+v1*q[1]+v2*q[2]+v3*q[3]+v4*q[4]
                  + v5*q[5]+v6*q[6]+v7*q[7]+v8*q[8]+v9*q[9];
        float gv = fmaxf(dot, 0.0f);
        g[(size_t)bn*NN + m] = gv;
        sum += gv;
    }
    #pragma unroll
    for (int off = 32; off > 0; off >>= 1) sum += __shfl_down(sum, off, 64);
    if (t == 0) dd[bn] = 1.0f / sqrtf(sum);
}

// C: Lx[b,n,i] = d[n] * sum_m g[n,m]*d[m]*cat[m,i]  (16 rows per block)
#define GR 16
__global__ __launch_bounds__(256) void mg_c(
    const float* __restrict__ g, const float* __restrict__ dd,
    const float* __restrict__ cat, float* __restrict__ lx)
{
    int blk = blockIdx.x;
    int b = blk / 20;
    int n0 = (blk % 20) * GR;
    int t = threadIdx.x;
    int j = t >> 4;
    int i0 = t & 15;
    __shared__ float catc[64][66];
    __shared__ float dc[64];
    __shared__ float gj[GR][64];
    float acc0=0.f, acc1=0.f, acc2=0.f, acc3=0.f, acc4=0.f;
    for (int m0 = 0; m0 < NN; m0 += 64) {
        for (int idx = t; idx < 64*65; idx += 256) {
            int ml = idx / 65, ii = idx % 65;
            int m = m0 + ml;
            catc[ml][ii] = (m < NN) ? cat[((size_t)b*NN + m)*NCIN + ii] : 0.f;
        }
        if (t < 64) {
            int m = m0 + t;
            dc[t] = (m < NN) ? dd[b*NN + m] : 0.f;
        }
        for (int idx = t; idx < GR*64; idx += 256) {
            int jj = idx >> 6, ml = idx & 63;
            int row = n0 + jj, m = m0 + ml;
            gj[jj][ml] = (row < NN && m < NN)
                       ? g[((size_t)b*NN + row)*NN + m] : 0.f;
        }
        __syncthreads();
        #pragma unroll 4
        for (int ml = 0; ml < 64; ++ml) {
            float coef = gj[j][ml] * dc[ml];
            acc0 += coef * catc[ml][i0];
            acc1 += coef * catc[ml][i0+16];
            acc2 += coef * catc[ml][i0+32];
            acc3 += coef * catc[ml][i0+48];
            acc4 += coef * catc[ml][64];
        }
        __syncthreads();
    }
    int row = n0 + j;
    if (row < NN) {
        float dn = dd[b*NN + row];
        size_t base = ((size_t)b*NN + row)*NCIN;
        lx[base + i0]      = dn*acc0;
        lx[base + i0+16]   = dn*acc1;
        lx[base + i0+32]   = dn*acc2;
        lx[base + i0+48]   = dn*acc3;
        if (i0 == 0) lx[base + 64] = dn*acc4;
    }
}

// D1: gates einsum -> zr=sigmoid(.); fused cand = [x, z*state] and MLP_u -> nv
__global__ __launch_bounds__(256) void mg_d1(
    const float* __restrict__ cat1, const float* __restrict__ lxb,
    const float* __restrict__ weff, const float* __restrict__ beff,
    const float* __restrict__ state,
    const float* __restrict__ xptr, int xbs, int xns,
    const float* __restrict__ ne0t,
    const float* __restrict__ u1w, const float* __restrict__ u1b,
    const float* __restrict__ u2w, const float* __restrict__ u2b,
    const float* __restrict__ u3w, const float* __restrict__ u3b,
    float* __restrict__ zr, float* __restrict__ cat2, float* __restrict__ nvout)
{
    int n = blockIdx.x >> 1;
    int b0 = (blockIdx.x & 1) * BG;
    int t = threadIdx.x;
    __shared__ float sin_[130][20];   // [i][b-local], padded stride 20 (16B-aligned rows)
    __shared__ float szr[BG][NO2];
    __shared__ float scand[BG][NCIN];
    __shared__ float sh1[BG][16];
    __shared__ float sh2[BG][2];
    for (int idx = t; idx < 130*BG; idx += 256) {
        int i = idx % 130, bb = idx / 130;
        int b = b0 + bb;
        float v = (i < NCIN) ? cat1[((size_t)b*NN+n)*NCIN + i]
                             : lxb[((size_t)b*NN+n)*NCIN + (i-NCIN)];
        sin_[i][bb] = v;
    }
    __syncthreads();
    int o = t & (NO2-1);
    int bs = t >> 7;   // 0..1 -> 8 batches each
    float acc[8];
    float bv = beff[n*NO2 + o];
    #pragma unroll
    for (int u = 0; u < 8; ++u) acc[u] = bv;
    const float* w0 = weff + (size_t)n * 2*NCIN*NO2;
    for (int i = 0; i < 130; ++i) {
        float w = w0[i*NO2 + o];
        const float4* s4 = (const float4*)&sin_[i][bs*8];
        float4 a = s4[0], c = s4[1];
        acc[0] += a.x*w; acc[1] += a.y*w; acc[2] += a.z*w; acc[3] += a.w*w;
        acc[4] += c.x*w; acc[5] += c.y*w; acc[6] += c.z*w; acc[7] += c.w*w;
    }
    #pragma unroll
    for (int u = 0; u < 8; ++u) {
        int bb = bs*8 + u;
        float zv = sigmoidf_(acc[u]);
        zr[((size_t)(b0+bb)*NN+n)*NO2 + o] = zv;
        szr[bb][o] = zv;
    }
    __syncthreads();
    for (int idx = t; idx < BG*NCIN; idx += 256) {
        int bb = idx / NCIN, i = idx % NCIN;
        int b = b0 + bb;
        float v;
        if (i == 0) v = xptr[(size_t)b*xbs + (size_t)n*xns];
        else        v = szr[bb][i-1] * state[((size_t)b*NN+n)*NH + (i-1)];
        scand[bb][i] = v;
        cat2[((size_t)b*NN+n)*NCIN + i] = v;
    }
    __syncthreads();
    {
        int bb = t >> 4, j = t & 15;
        float a = u1b[j];
        const float* w = u1w + j*NCIN;
        #pragma unroll
        for (int i = 0; i < NCIN; ++i) a += scand[bb][i] * w[i];
        sh1[bb][j] = sigmoidf_(a);
    }
    __syncthreads();
    if (t < BG*2) {
        int bb = t >> 1, j = t & 1;
        float a = u2b[j];
        const float* w = u2w + j*16;
        #pragma unroll
        for (int i = 0; i < 16; ++i) a += sh1[bb][i] * w[i];
        sh2[bb][j] = sigmoidf_(a);
    }
    __syncthreads();
    if (t < BG*NE) {
        int bb = t / NE, e = t % NE;
        int b = b0 + bb;
        float xe = sh2[bb][0]*u3w[e*2] + sh2[bb][1]*u3w[e*2+1] + u3b[e];
        nvout[((size_t)b*NN+n)*NE + e] =
            tanhf(ne0t[(size_t)b*NT*NN*NE + n*NE + e] * xe);
    }
}

// D2f: candidate einsum -> hc; GRU update; then (optionally) build NEXT step's
// cat1 and run the next cell's g-MLP -> nv  (replaces next mg_a).
__global__ __launch_bounds__(256) void mg_d2f(
    const float* __restrict__ cat2, const float* __restrict__ lxb,
    const float* __restrict__ weff, const float* __restrict__ beff,
    const float* __restrict__ zr,
    float* __restrict__ state, float* __restrict__ outi,
    int same_chain, const float* __restrict__ state_next,
    const float* __restrict__ xn, int xbs, int xns,
    const float* __restrict__ ne0n,
    const float* __restrict__ w1n, const float* __restrict__ b1n,
    const float* __restrict__ w2n, const float* __restrict__ b2n,
    const float* __restrict__ w3n, const float* __restrict__ b3n,
    float* __restrict__ cat1, float* __restrict__ nvout)
{
    int n = blockIdx.x >> 1;
    int b0 = (blockIdx.x & 1) * BG;
    int t = threadIdx.x;
    __shared__ float sin_[130][20];
    __shared__ float shh[BG][NH];     // freshly updated h
    __shared__ float scand[BG][NCIN];
    __shared__ float sh1[BG][16];
    __shared__ float sh2[BG][2];
    for (int idx = t; idx < 130*BG; idx += 256) {
        int i = idx % 130, bb = idx / 130;
        int b = b0 + bb;
        float v = (i < NCIN) ? cat2[((size_t)b*NN+n)*NCIN + i]
                             : lxb[((size_t)b*NN+n)*NCIN + (i-NCIN)];
        sin_[i][bb] = v;
    }
    __syncthreads();
    int o = t & (NH-1);
    int bs = t >> 6;   // 0..3 -> 4 batches each
    float acc[4];
    float bv = beff[n*NH + o];
    #pragma unroll
    for (int u = 0; u < 4; ++u) acc[u] = bv;
    const float* w0 = weff + (size_t)n * 2*NCIN*NH;
    for (int i = 0; i < 130; ++i) {
        float w = w0[i*NH + o];
        const float4* s4 = (const float4*)&sin_[i][bs*4];
        float4 a = s4[0];
        acc[0] += a.x*w; acc[1] += a.y*w; acc[2] += a.z*w; acc[3] += a.w*w;
    }
    #pragma unroll
    for (int u = 0; u < 4; ++u) {
        int bb = bs*4 + u;
        int b = b0 + bb;
        float hc = tanhf(acc[u]);
        size_t sb = ((size_t)b*NN+n)*NH + o;
        float st = state[sb];
        float r = zr[((size_t)b*NN+n)*NO2 + NH + o];
        float h = r*st + (1.0f - r)*hc;
        state[sb] = h;
        shh[bb][o] = h;
        if (outi) outi[(size_t)b*2*NN*NH + (size_t)n*NH + o] = h;
    }
    if (!w1n) return;
    __syncthreads();
    // build next-step cat1 = [x_{t+1}, state_{t+1}]
    for (int idx = t; idx < BG*NCIN; idx += 256) {
        int bb = idx / NCIN, i = idx % NCIN;
        int b = b0 + bb;
        float v;
        if (i == 0)          v = xn[(size_t)b*xbs + (size_t)n*xns];
        else if (same_chain) v = shh[bb][i-1];
        else                 v = state_next[((size_t)b*NN+n)*NH + (i-1)];
        scand[bb][i] = v;
        cat1[((size_t)b*NN+n)*NCIN + i] = v;
    }
    __syncthreads();
    {
        int bb = t >> 4, j = t & 15;
        float a = b1n[j];
        const float* w = w1n + j*NCIN;
        #pragma unroll
        for (int i = 0; i < NCIN; ++i) a += scand[bb][i] * w[i];
        sh1[bb][j] = sigmoidf_(a);
    }
    __syncthreads();
    if (t < BG*2) {
        int bb = t >> 1, j = t & 1;
        float a = b2n[j];
        const float* w = w2n + j*16;
        #pragma unroll
        for (int i = 0; i < 16; ++i) a += sh1[bb][i] * w[i];
        sh2[bb][j] = sigmoidf_(a);
    }
    __syncthreads();
    if (t < BG*NE) {
        int bb = t / NE, e = t % NE;
        int b = b0 + bb;
        float xe = sh2[bb][0]*w3n[e*2] + sh2[bb][1]*w3n[e*2+1] + b3n[e];
        nvout[((size_t)b*NN+n)*NE + e] =
            tanhf(ne0n[(size_t)b*NT*NN*NE + n*NE + e] * xe);
    }
}

// skip conv between layers: x2 = conv(out1) + flow
__global__ void mg_conv(
    const float* __restrict__ out1, const float* __restrict__ skip_w,
    const float* __restrict__ skip_b, const float* __restrict__ src,
    float* __restrict__ x2)
{
    int idx = blockIdx.x*blockDim.x + threadIdx.x;
    if (idx >= NB*NT*NN) return;
    int n = idx % NN; int r = idx / NN; int o = r % NT; int b = r / NT;
    float acc = skip_b[o];
    #pragma unroll
    for (int c = 0; c < 2; ++c) {
        const float* p = out1 + ((size_t)(b*2+c)*NN + n)*NH;
        const float* w = skip_w + (o*2+c)*NH;
        #pragma unroll
        for (int k = 0; k < NH; ++k) acc += p[k]*w[k];
    }
    x2[idx] = acc + src[(size_t)idx*5];
}

// layernorm over concat(out1,out2) + end conv -> output
__global__ __launch_bounds__(128) void mg_final(
    const float* __restrict__ out1, const float* __restrict__ out2,
    const float* __restrict__ ln_g, const float* __restrict__ ln_b,
    const float* __restrict__ end_w, const float* __restrict__ end_b,
    float* __restrict__ dout)
{
    int bn = blockIdx.x;
    int b = bn / NN, n = bn % NN;
    int t = threadIdx.x;
    __shared__ float snorm[2][NO2];
    __shared__ float red[2];
    for (int c = 0; c < 2; ++c) {
        size_t base = ((size_t)(b*2+c)*NN + n)*NH;
        float p = (t < NH) ? out1[base + t] : out2[base + (t - NH)];
        float s = p;
        #pragma unroll
        for (int off = 32; off > 0; off >>= 1) s += __shfl_down(s, off, 64);
        if ((t & 63) == 0) red[t >> 6] = s;
        __syncthreads();
        float m = (red[0] + red[1]) * (1.0f/128.0f);
        __syncthreads();
        float df = p - m;
        float s2 = df*df;
        #pragma unroll
        for (int off = 32; off > 0; off >>= 1) s2 += __shfl_down(s2, off, 64);
        if ((t & 63) == 0) red[t >> 6] = s2;
        __syncthreads();
        float v = (red[0] + red[1]) * (1.0f/128.0f);
        snorm[c][t] = df / sqrtf(v + 1e-12f) * ln_g[t] + ln_b[t];
        __syncthreads();
    }
    if (t < NT) {
        float a = end_b[t];
        const float* w = end_w + t*2*NO2;
        for (int c = 0; c < 2; ++c)
            for (int j = 0; j < NO2; ++j)
                a += snorm[c][j] * w[c*NO2 + j];
        dout[(size_t)(b*NT + t)*NN + n] = a;
    }
}

// ---------------- host ----------------

extern "C" void kernel_launch(void* const* d_in, const int* in_sizes, int n_in,
                              void* d_out, int out_size, void* d_ws, size_t ws_size,
                              hipStream_t stream)
{
    const float* src      = (const float*)d_in[0];
    const float* node_emb = (const float*)d_in[1];
    const float* tid_emb  = (const float*)d_in[2];
    const float* dow_emb  = (const float*)d_in[3];
    const float* hol_emb  = (const float*)d_in[4];
    const float* hop_w    = (const float*)d_in[5];
    const float* hop_b    = (const float*)d_in[6];
    const float* gw  = (const float*)d_in[7];
    const float* gb  = (const float*)d_in[8];
    const float* g1w = (const float*)d_in[9];
    const float* g1b = (const float*)d_in[10];
    const float* g2w = (const float*)d_in[11];
    const float* g2b = (const float*)d_in[12];
    const float* g3w = (const float*)d_in[13];
    const float* g3b = (const float*)d_in[14];
    const float* uw  = (const float*)d_in[15];
    const float* ub  = (const float*)d_in[16];
    const float* u1w = (const float*)d_in[17];
    const float* u1b = (const float*)d_in[18];
    const float* u2w = (const float*)d_in[19];
    const float* u2b = (const float*)d_in[20];
    const float* u3w = (const float*)d_in[21];
    const float* u3b = (const float*)d_in[22];
    const float* skip_w = (const float*)d_in[23];
    const float* skip_b = (const float*)d_in[24];
    const float* ln_g = (const float*)d_in[25];
    const float* ln_b = (const float*)d_in[26];
    const float* end_w = (const float*)d_in[27];
    const float* end_b = (const float*)d_in[28];
    float* dout = (float*)d_out;

    float* ws = (float*)d_ws;
    size_t off = 0;
    float* weff_g = ws + off; off += (size_t)3*NN*2*NCIN*NO2;  // 15.3M
    float* weff_u = ws + off; off += (size_t)3*NN*2*NCIN*NH;   // 7.7M
    float* beff_g = ws + off; off += (size_t)3*NN*NO2;
    float* beff_u = ws + off; off += (size_t)3*NN*NH;
    float* ne0    = ws + off; off += (size_t)NB*NT*NN*NE;
    float* st     = ws + off; off += (size_t)2*NB*NN*NH;
    float* cat1   = ws + off; off += (size_t)NB*NN*NCIN;
    float* cat2   = ws + off; off += (size_t)NB*NN*NCIN;
    float* nv     = ws + off; off += (size_t)NB*NN*NE;
    float* gbuf   = ws + off; off += (size_t)NB*NN*NN;         // 3.0M
    float* dd     = ws + off; off += (size_t)NB*NN;
    float* lx     = ws + off; off += (size_t)NB*NN*NCIN;
    float* zr     = ws + off; off += (size_t)NB*NN*NO2;
    float* out1   = ws + off; off += (size_t)NB*2*NN*NH;
    float* out2   = ws + off; off += (size_t)NB*2*NN*NH;
    float* x2     = ws + off; off += (size_t)NB*NT*NN;

    mg_ne0<<<(NB*NT*NN + 255)/256, 256, 0, stream>>>(
        src, node_emb, tid_emb, dow_emb, hol_emb, hop_w, hop_b, ne0);
    mg_weff<<<4096, 256, 0, stream>>>(
        node_emb, gw, gb, uw, ub, weff_g, beff_g, weff_u, beff_u);

    const int stcount = 2*NB*NN*NH;
    mg_zero<<<(stcount+255)/256, 256, 0, stream>>>(st, stcount);

    // per-cell MLP-g weight pointers
    auto G1W = [&](int c){ return g1w + c*16*NCIN; };
    auto G1B = [&](int c){ return g1b + c*16; };
    auto G2W = [&](int c){ return g2w + c*2*16; };
    auto G2B = [&](int c){ return g2b + c*2; };
    auto G3W = [&](int c){ return g3w + c*NE*2; };
    auto G3B = [&](int c){ return g3b + c*NE; };

    // ---- layer 1 (cell 0, single state chain) ----
    for (int t = 0; t < NT; ++t) {
        const float* ne0t = ne0 + (size_t)t*NN*NE;
        const float* xptr = src + (size_t)t*NN*5;
        float* outi = (t >= NT-2) ? (out1 + (size_t)(t-(NT-2))*NN*NH) : nullptr;
        if (t == 0) {
            mg_a<<<NB*NN, 64, 0, stream>>>(st, xptr, NT*NN*5, 5, ne0t,
                G1W(0), G1B(0), G2W(0), G2B(0), G3W(0), G3B(0), cat1, nv);
        }
        mg_b<<<NB*NN, 64, 0, stream>>>(nv, gbuf, dd);
        mg_c<<<NB*20, 256, 0, stream>>>(gbuf, dd, cat1, lx);
        mg_d1<<<NN*(NB/BG), 256, 0, stream>>>(cat1, lx,
            weff_g, beff_g, st, xptr, NT*NN*5, 5, ne0t,
            u1w, u1b, u2w, u2b, u3w, u3b, zr, cat2, nv);
        mg_b<<<NB*NN, 64, 0, stream>>>(nv, gbuf, dd);
        mg_c<<<NB*20, 256, 0, stream>>>(gbuf, dd, cat2, lx);
        bool fuse = (t < NT-1);
        const float* xn   = fuse ? (src + (size_t)(t+1)*NN*5) : nullptr;
        const float* ne0n = fuse ? (ne0 + (size_t)(t+1)*NN*NE) : nullptr;
        mg_d2f<<<NN*(NB/BG), 256, 0, stream>>>(cat2, lx,
            weff_u, beff_u, zr, st, outi,
            /*same_chain=*/1, /*state_next=*/st,
            xn, NT*NN*5, 5, ne0n,
            fuse ? G1W(0) : nullptr, G1B(0), G2W(0), G2B(0), G3W(0), G3B(0),
            cat1, nv);
    }
    mg_conv<<<(NB*NT*NN+255)/256, 256, 0, stream>>>(out1, skip_w, skip_b, src, x2);
    mg_zero<<<(stcount+255)/256, 256, 0, stream>>>(st, stcount);

    // ---- layer 2 (cells 1,2 alternating, two state chains) ----
    for (int t = 0; t < NT; ++t) {
        int c = 1 + (t & 1);
        float* state = st + (size_t)(t & 1)*NB*NN*NH;
        const float* ne0t = ne0 + (size_t)t*NN*NE;
        const float* xptr = x2 + (size_t)t*NN;
        float* outi = (t >= NT-2) ? (out2 + (size_t)(t-(NT-2))*NN*NH) : nullptr;
        if (t == 0) {
            mg_a<<<NB*NN, 64, 0, stream>>>(state, xptr, NT*NN, 1, ne0t,
                G1W(c), G1B(c), G2W(c), G2B(c), G3W(c), G3B(c), cat1, nv);
        }
        mg_b<<<NB*NN, 64, 0, stream>>>(nv, gbuf, dd);
        mg_c<<<NB*20, 256, 0, stream>>>(gbuf, dd, cat1, lx);
        mg_d1<<<NN*(NB/BG), 256, 0, stream>>>(cat1, lx,
            weff_g + (size_t)c*NN*2*NCIN*NO2, beff_g + (size_t)c*NN*NO2,
            state, xptr, NT*NN, 1, ne0t,
            u1w + c*16*NCIN, u1b + c*16, u2w + c*2*16, u2b + c*2,
            u3w + c*NE*2, u3b + c*NE, zr, cat2, nv);
        mg_b<<<NB*NN, 64, 0, stream>>>(nv, gbuf, dd);
        mg_c<<<NB*20, 256, 0, stream>>>(gbuf, dd, cat2, lx);
        bool fuse = (t < NT-1);
        int cn = 1 + ((t+1) & 1);
        float* chain_next = st + (size_t)((t+1) & 1)*NB*NN*NH;
        const float* xn   = fuse ? (x2 + (size_t)(t+1)*NN) : nullptr;
        const float* ne0n = fuse ? (ne0 + (size_t)(t+1)*NN*NE) : nullptr;
        mg_d2f<<<NN*(NB/BG), 256, 0, stream>>>(cat2, lx,
            weff_u + (size_t)c*NN*2*NCIN*NH, beff_u + (size_t)c*NN*NH,
            zr, state, outi,
            /*same_chain=*/0, /*state_next=*/chain_next,
            xn, NT*NN, 1, ne0n,
            fuse ? G1W(cn) : nullptr, G1B(cn), G2W(cn), G2B(cn), G3W(cn), G3B(cn),
            cat1, nv);
    }
    mg_final<<<NB*NN, 128, 0, stream>>>(out1, out2, ln_g, ln_b, end_w, end_b, dout);
}

// Round 13
// 3733.878 us; speedup vs baseline: 1.8196x; 1.1457x over previous
//
#include <hip/hip_runtime.h>
#include <hip/hip_cooperative_groups.h>
#include <math.h>

namespace cg = cooperative_groups;

#define NB 32      // batch
#define NT 12      // time steps
#define NN 307     // nodes
#define NE 10      // embedding dim
#define NH 64      // hidden
#define NCIN 65    // 1 + H
#define NO2 128    // 2H
#define BG 16      // batches per einsum block
#define GR 16      // rows per C-tile
#define GB 512     // cooperative grid blocks (2 blocks/CU x 256 CU)
#define GWAVES (GB*4)

__device__ __forceinline__ float sigmoidf_(float x) {
    return 1.0f / (1.0f + __expf(-x));
}

// ---------------- precompute ----------------

__global__ void mg_ne0(const float* __restrict__ src,
                       const float* __restrict__ node_emb,
                       const float* __restrict__ tid_emb,
                       const float* __restrict__ dow_emb,
                       const float* __restrict__ hol_emb,
                       const float* __restrict__ hop_w,
                       const float* __restrict__ hop_b,
                       float* __restrict__ ne0)
{
    int idx = blockIdx.x * blockDim.x + threadIdx.x;
    const int total = NB * NT * NN;
    if (idx >= total) return;
    int n = idx % NN;
    const float* s = src + (size_t)idx * 5;
    int ti = (int)(s[1] * 288.0f); ti = ti < 0 ? 0 : (ti > 287 ? 287 : ti);
    int dw = (int)s[2];            dw = dw < 0 ? 0 : (dw > 6 ? 6 : dw);
    int hl = (int)s[3];            hl = hl < 0 ? 0 : (hl > 1 ? 1 : hl);
    float hop = s[4];
    float* o = ne0 + (size_t)idx * NE;
    #pragma unroll
    for (int e = 0; e < NE; ++e) {
        float v = node_emb[n*NE+e] * tid_emb[ti*NE+e] * dow_emb[dw*NE+e] * hol_emb[hl*NE+e];
        o[e] = v * (hop * hop_w[e] + hop_b[e]);
    }
}

__global__ void mg_weff(const float* __restrict__ node_emb,
                        const float* __restrict__ gw, const float* __restrict__ gb,
                        const float* __restrict__ uw, const float* __restrict__ ub,
                        float* __restrict__ weff_g, float* __restrict__ beff_g,
                        float* __restrict__ weff_u, float* __restrict__ beff_u)
{
    const int NG  = 3*NN*2*NCIN*NO2;
    const int NU  = 3*NN*2*NCIN*NH;
    const int NBG = 3*NN*NO2;
    const int NBU = 3*NN*NH;
    int total = NG + NU + NBG + NBU;
    for (int idx = blockIdx.x*blockDim.x + threadIdx.x; idx < total;
         idx += gridDim.x*blockDim.x) {
        if (idx < NG) {
            int j = idx;
            int o = j & (NO2-1); j >>= 7;
            int i = j % NCIN;    j /= NCIN;
            int k = j & 1;       j >>= 1;
            int n = j % NN;      int c = j / NN;
            float a = 0.f;
            #pragma unroll
            for (int e = 0; e < NE; ++e)
                a += node_emb[n*NE+e] * gw[(((c*NE+e)*2+k)*NCIN+i)*NO2 + o];
            weff_g[idx] = a;
        } else if (idx < NG + NU) {
            int j = idx - NG; int jo = j;
            int o = j & (NH-1); j >>= 6;
            int i = j % NCIN;   j /= NCIN;
            int k = j & 1;      j >>= 1;
            int n = j % NN;     int c = j / NN;
            float a = 0.f;
            #pragma unroll
            for (int e = 0; e < NE; ++e)
                a += node_emb[n*NE+e] * uw[(((c*NE+e)*2+k)*NCIN+i)*NH + o];
            weff_u[jo] = a;
        } else if (idx < NG + NU + NBG) {
            int j = idx - NG - NU;
            int o = j & (NO2-1);
            int n = (j >> 7) % NN; int c = (j >> 7) / NN;
            float a = 0.f;
            #pragma unroll
            for (int e = 0; e < NE; ++e)
                a += node_emb[n*NE+e] * gb[(c*NE+e)*NO2 + o];
            beff_g[j] = a;
        } else {
            int j = idx - NG - NU - NBG;
            int o = j & (NH-1);
            int n = (j >> 6) % NN; int c = (j >> 6) / NN;
            float a = 0.f;
            #pragma unroll
            for (int e = 0; e < NE; ++e)
                a += node_emb[n*NE+e] * ub[(c*NE+e)*NH + o];
            beff_u[j] = a;
        }
    }
}

__global__ void mg_zero(float* __restrict__ p, int count) {
    int idx = blockIdx.x * blockDim.x + threadIdx.x;
    if (idx < count) p[idx] = 0.0f;
}

// A: build cat = [x, state], run small MLP -> nv  (t=0 of each layer)
__global__ __launch_bounds__(64) void mg_a(
    const float* __restrict__ state,
    const float* __restrict__ xptr, int xbs, int xns,
    const float* __restrict__ ne0t,
    const float* __restrict__ w1, const float* __restrict__ b1,
    const float* __restrict__ w2, const float* __restrict__ b2,
    const float* __restrict__ w3, const float* __restrict__ b3,
    float* __restrict__ cat, float* __restrict__ nvout)
{
    int bn = blockIdx.x;
    int b = bn / NN, n = bn % NN;
    int t = threadIdx.x;
    __shared__ float sc[NCIN];
    __shared__ float sh1[16];
    __shared__ float sh2[2];
    float st = state[(size_t)bn*NH + t];
    sc[1+t] = st;
    cat[(size_t)bn*NCIN + 1 + t] = st;
    if (t == 0) {
        float xv = xptr[(size_t)b*xbs + (size_t)n*xns];
        sc[0] = xv;
        cat[(size_t)bn*NCIN] = xv;
    }
    __syncthreads();
    if (t < 16) {
        float a = b1[t];
        const float* w = w1 + t*NCIN;
        #pragma unroll
        for (int i = 0; i < NCIN; ++i) a += sc[i] * w[i];
        sh1[t] = sigmoidf_(a);
    }
    __syncthreads();
    if (t < 2) {
        float a = b2[t];
        const float* w = w2 + t*16;
        #pragma unroll
        for (int i = 0; i < 16; ++i) a += sh1[i] * w[i];
        sh2[t] = sigmoidf_(a);
    }
    __syncthreads();
    if (t < NE) {
        float xe = sh2[0]*w3[t*2] + sh2[1]*w3[t*2+1] + b3[t];
        nvout[(size_t)bn*NE + t] =
            tanhf(ne0t[(size_t)b*NT*NN*NE + n*NE + t] * xe);
    }
}

// B: g row + d (fallback standalone)
__global__ __launch_bounds__(64) void mg_b(
    const float* __restrict__ nv, float* __restrict__ g, float* __restrict__ dd)
{
    int bn = blockIdx.x;
    int b = bn / NN;
    int t = threadIdx.x;
    __shared__ float snv[NE];
    if (t < NE) snv[t] = nv[(size_t)bn*NE + t];
    __syncthreads();
    float v0=snv[0],v1=snv[1],v2=snv[2],v3=snv[3],v4=snv[4],
          v5=snv[5],v6=snv[6],v7=snv[7],v8=snv[8],v9=snv[9];
    float sum = 0.0f;
    for (int m = t; m < NN; m += 64) {
        const float* q = nv + ((size_t)b*NN + m)*NE;
        float dot = v0*q[0]+v1*q[1]+v2*q[2]+v3*q[3]+v4*q[4]
                  + v5*q[5]+v6*q[6]+v7*q[7]+v8*q[8]+v9*q[9];
        float gv = fmaxf(dot, 0.0f);
        g[(size_t)bn*NN + m] = gv;
        sum += gv;
    }
    #pragma unroll
    for (int off = 32; off > 0; off >>= 1) sum += __shfl_down(sum, off, 64);
    if (t == 0) dd[bn] = 1.0f / sqrtf(sum);
}

// ---------------- shared phase bodies ----------------

struct SMC  { float catc[64][66]; float dc[64]; float gj[GR][64]; };
struct SMD1 { float sin_[130][20]; float szr[BG][NO2]; float scand[BG][NCIN];
              float sh1[BG][16]; float sh2[BG][2]; };
struct SMD2 { float sin_[130][20]; float shh[BG][NH]; float scand[BG][NCIN];
              float sh1[BG][16]; float sh2[BG][2]; };

__device__ void phaseC_body(const float* __restrict__ g, const float* __restrict__ dd,
                            const float* __restrict__ cat, float* __restrict__ lx,
                            char* smraw, int vb, int tid)
{
    SMC& s = *reinterpret_cast<SMC*>(smraw);
    int b = vb / 20;
    int n0 = (vb % 20) * GR;
    int j = tid >> 4;
    int i0 = tid & 15;
    float acc0=0.f, acc1=0.f, acc2=0.f, acc3=0.f, acc4=0.f;
    for (int m0 = 0; m0 < NN; m0 += 64) {
        for (int idx = tid; idx < 64*65; idx += 256) {
            int ml = idx / 65, ii = idx % 65;
            int m = m0 + ml;
            s.catc[ml][ii] = (m < NN) ? cat[((size_t)b*NN + m)*NCIN + ii] : 0.f;
        }
        if (tid < 64) {
            int m = m0 + tid;
            s.dc[tid] = (m < NN) ? dd[b*NN + m] : 0.f;
        }
        for (int idx = tid; idx < GR*64; idx += 256) {
            int jj = idx >> 6, ml = idx & 63;
            int row = n0 + jj, m = m0 + ml;
            s.gj[jj][ml] = (row < NN && m < NN)
                         ? g[((size_t)b*NN + row)*NN + m] : 0.f;
        }
        __syncthreads();
        #pragma unroll 4
        for (int ml = 0; ml < 64; ++ml) {
            float coef = s.gj[j][ml] * s.dc[ml];
            acc0 += coef * s.catc[ml][i0];
            acc1 += coef * s.catc[ml][i0+16];
            acc2 += coef * s.catc[ml][i0+32];
            acc3 += coef * s.catc[ml][i0+48];
            acc4 += coef * s.catc[ml][64];
        }
        __syncthreads();
    }
    int row = n0 + j;
    if (row < NN) {
        float dn = dd[b*NN + row];
        size_t base = ((size_t)b*NN + row)*NCIN;
        lx[base + i0]      = dn*acc0;
        lx[base + i0+16]   = dn*acc1;
        lx[base + i0+32]   = dn*acc2;
        lx[base + i0+48]   = dn*acc3;
        if (i0 == 0) lx[base + 64] = dn*acc4;
    }
}

__device__ void phaseD1_body(const float* __restrict__ cat1, const float* __restrict__ lxb,
                             const float* __restrict__ weff, const float* __restrict__ beff,
                             const float* __restrict__ state,
                             const float* __restrict__ xptr, int xbs, int xns,
                             const float* __restrict__ ne0t,
                             const float* __restrict__ u1w, const float* __restrict__ u1b,
                             const float* __restrict__ u2w, const float* __restrict__ u2b,
                             const float* __restrict__ u3w, const float* __restrict__ u3b,
                             float* __restrict__ zr, float* __restrict__ cat2,
                             float* __restrict__ nvout,
                             char* smraw, int vb, int t)
{
    SMD1& s = *reinterpret_cast<SMD1*>(smraw);
    int n = vb >> 1;
    int b0 = (vb & 1) * BG;
    for (int idx = t; idx < 130*BG; idx += 256) {
        int i = idx % 130, bb = idx / 130;
        int b = b0 + bb;
        float v = (i < NCIN) ? cat1[((size_t)b*NN+n)*NCIN + i]
                             : lxb[((size_t)b*NN+n)*NCIN + (i-NCIN)];
        s.sin_[i][bb] = v;
    }
    __syncthreads();
    int o = t & (NO2-1);
    int bs = t >> 7;
    float acc[8];
    float bv = beff[n*NO2 + o];
    #pragma unroll
    for (int u = 0; u < 8; ++u) acc[u] = bv;
    const float* w0 = weff + (size_t)n * 2*NCIN*NO2;
    for (int i = 0; i < 130; ++i) {
        float w = w0[i*NO2 + o];
        const float4* s4 = (const float4*)&s.sin_[i][bs*8];
        float4 a = s4[0], c = s4[1];
        acc[0] += a.x*w; acc[1] += a.y*w; acc[2] += a.z*w; acc[3] += a.w*w;
        acc[4] += c.x*w; acc[5] += c.y*w; acc[6] += c.z*w; acc[7] += c.w*w;
    }
    #pragma unroll
    for (int u = 0; u < 8; ++u) {
        int bb = bs*8 + u;
        float zv = sigmoidf_(acc[u]);
        zr[((size_t)(b0+bb)*NN+n)*NO2 + o] = zv;
        s.szr[bb][o] = zv;
    }
    __syncthreads();
    for (int idx = t; idx < BG*NCIN; idx += 256) {
        int bb = idx / NCIN, i = idx % NCIN;
        int b = b0 + bb;
        float v;
        if (i == 0) v = xptr[(size_t)b*xbs + (size_t)n*xns];
        else        v = s.szr[bb][i-1] * state[((size_t)b*NN+n)*NH + (i-1)];
        s.scand[bb][i] = v;
        cat2[((size_t)b*NN+n)*NCIN + i] = v;
    }
    __syncthreads();
    {
        int bb = t >> 4, j = t & 15;
        float a = u1b[j];
        const float* w = u1w + j*NCIN;
        #pragma unroll
        for (int i = 0; i < NCIN; ++i) a += s.scand[bb][i] * w[i];
        s.sh1[bb][j] = sigmoidf_(a);
    }
    __syncthreads();
    if (t < BG*2) {
        int bb = t >> 1, j = t & 1;
        float a = u2b[j];
        const float* w = u2w + j*16;
        #pragma unroll
        for (int i = 0; i < 16; ++i) a += s.sh1[bb][i] * w[i];
        s.sh2[bb][j] = sigmoidf_(a);
    }
    __syncthreads();
    if (t < BG*NE) {
        int bb = t / NE, e = t % NE;
        int b = b0 + bb;
        float xe = s.sh2[bb][0]*u3w[e*2] + s.sh2[bb][1]*u3w[e*2+1] + u3b[e];
        nvout[((size_t)b*NN+n)*NE + e] =
            tanhf(ne0t[(size_t)b*NT*NN*NE + n*NE + e] * xe);
    }
}

__device__ void phaseD2_body(const float* __restrict__ cat2, const float* __restrict__ lxb,
                             const float* __restrict__ weff, const float* __restrict__ beff,
                             const float* __restrict__ zr,
                             float* __restrict__ state, float* __restrict__ outi,
                             int same_chain, const float* __restrict__ state_next,
                             const float* __restrict__ xn, int xbs, int xns,
                             const float* __restrict__ ne0n,
                             const float* __restrict__ w1n, const float* __restrict__ b1n,
                             const float* __restrict__ w2n, const float* __restrict__ b2n,
                             const float* __restrict__ w3n, const float* __restrict__ b3n,
                             float* __restrict__ cat1, float* __restrict__ nvout,
                             char* smraw, int vb, int t)
{
    SMD2& s = *reinterpret_cast<SMD2*>(smraw);
    int n = vb >> 1;
    int b0 = (vb & 1) * BG;
    for (int idx = t; idx < 130*BG; idx += 256) {
        int i = idx % 130, bb = idx / 130;
        int b = b0 + bb;
        float v = (i < NCIN) ? cat2[((size_t)b*NN+n)*NCIN + i]
                             : lxb[((size_t)b*NN+n)*NCIN + (i-NCIN)];
        s.sin_[i][bb] = v;
    }
    __syncthreads();
    int o = t & (NH-1);
    int bs = t >> 6;
    float acc[4];
    float bv = beff[n*NH + o];
    #pragma unroll
    for (int u = 0; u < 4; ++u) acc[u] = bv;
    const float* w0 = weff + (size_t)n * 2*NCIN*NH;
    for (int i = 0; i < 130; ++i) {
        float w = w0[i*NH + o];
        const float4* s4 = (const float4*)&s.sin_[i][bs*4];
        float4 a = s4[0];
        acc[0] += a.x*w; acc[1] += a.y*w; acc[2] += a.z*w; acc[3] += a.w*w;
    }
    #pragma unroll
    for (int u = 0; u < 4; ++u) {
        int bb = bs*4 + u;
        int b = b0 + bb;
        float hc = tanhf(acc[u]);
        size_t sb = ((size_t)b*NN+n)*NH + o;
        float st = state[sb];
        float r = zr[((size_t)b*NN+n)*NO2 + NH + o];
        float h = r*st + (1.0f - r)*hc;
        state[sb] = h;
        s.shh[bb][o] = h;
        if (outi) outi[(size_t)b*2*NN*NH + (size_t)n*NH + o] = h;
    }
    if (!w1n) return;
    __syncthreads();
    for (int idx = t; idx < BG*NCIN; idx += 256) {
        int bb = idx / NCIN, i = idx % NCIN;
        int b = b0 + bb;
        float v;
        if (i == 0)          v = xn[(size_t)b*xbs + (size_t)n*xns];
        else if (same_chain) v = s.shh[bb][i-1];
        else                 v = state_next[((size_t)b*NN+n)*NH + (i-1)];
        s.scand[bb][i] = v;
        cat1[((size_t)b*NN+n)*NCIN + i] = v;
    }
    __syncthreads();
    {
        int bb = t >> 4, j = t & 15;
        float a = b1n[j];
        const float* w = w1n + j*NCIN;
        #pragma unroll
        for (int i = 0; i < NCIN; ++i) a += s.scand[bb][i] * w[i];
        s.sh1[bb][j] = sigmoidf_(a);
    }
    __syncthreads();
    if (t < BG*2) {
        int bb = t >> 1, j = t & 1;
        float a = b2n[j];
        const float* w = w2n + j*16;
        #pragma unroll
        for (int i = 0; i < 16; ++i) a += s.sh1[bb][i] * w[i];
        s.sh2[bb][j] = sigmoidf_(a);
    }
    __syncthreads();
    if (t < BG*NE) {
        int bb = t / NE, e = t % NE;
        int b = b0 + bb;
        float xe = s.sh2[bb][0]*w3n[e*2] + s.sh2[bb][1]*w3n[e*2+1] + b3n[e];
        nvout[((size_t)b*NN+n)*NE + e] =
            tanhf(ne0n[(size_t)b*NT*NN*NE + n*NE + e] * xe);
    }
}

// ---------------- fallback standalone kernels (validated round-11 bodies) ----------------

__global__ __launch_bounds__(256) void mg_c(
    const float* __restrict__ g, const float* __restrict__ dd,
    const float* __restrict__ cat, float* __restrict__ lx)
{
    __shared__ alignas(16) char smraw[sizeof(SMC)];
    phaseC_body(g, dd, cat, lx, smraw, blockIdx.x, threadIdx.x);
}

__global__ __launch_bounds__(256) void mg_d1(
    const float* __restrict__ cat1, const float* __restrict__ lxb,
    const float* __restrict__ weff, const float* __restrict__ beff,
    const float* __restrict__ state,
    const float* __restrict__ xptr, int xbs, int xns,
    const float* __restrict__ ne0t,
    const float* __restrict__ u1w, const float* __restrict__ u1b,
    const float* __restrict__ u2w, const float* __restrict__ u2b,
    const float* __restrict__ u3w, const float* __restrict__ u3b,
    float* __restrict__ zr, float* __restrict__ cat2, float* __restrict__ nvout)
{
    __shared__ alignas(16) char smraw[sizeof(SMD1)];
    phaseD1_body(cat1, lxb, weff, beff, state, xptr, xbs, xns, ne0t,
                 u1w, u1b, u2w, u2b, u3w, u3b, zr, cat2, nvout,
                 smraw, blockIdx.x, threadIdx.x);
}

__global__ __launch_bounds__(256) void mg_d2f(
    const float* __restrict__ cat2, const float* __restrict__ lxb,
    const float* __restrict__ weff, const float* __restrict__ beff,
    const float* __restrict__ zr,
    float* __restrict__ state, float* __restrict__ outi,
    int same_chain, const float* __restrict__ state_next,
    const float* __restrict__ xn, int xbs, int xns,
    const float* __restrict__ ne0n,
    const float* __restrict__ w1n, const float* __restrict__ b1n,
    const float* __restrict__ w2n, const float* __restrict__ b2n,
    const float* __restrict__ w3n, const float* __restrict__ b3n,
    float* __restrict__ cat1, float* __restrict__ nvout)
{
    __shared__ alignas(16) char smraw[sizeof(SMD2)];
    phaseD2_body(cat2, lxb, weff, beff, zr, state, outi, same_chain, state_next,
                 xn, xbs, xns, ne0n, w1n, b1n, w2n, b2n, w3n, b3n,
                 cat1, nvout, smraw, blockIdx.x, threadIdx.x);
}

// ---------------- cooperative layer kernel ----------------

struct LP {
    const float* x; long long xt; int xb, xn;
    const float* ne0;
    const float* weffg; const float* beffg;
    const float* weffu; const float* beffu;
    const float* g1w; const float* g1b; const float* g2w; const float* g2b;
    const float* g3w; const float* g3b;
    const float* u1w; const float* u1b; const float* u2w; const float* u2b;
    const float* u3w; const float* u3b;
    float* st; float* cat1; float* cat2; float* nv; float* g; float* dd;
    float* lx; float* zr; float* outbuf; int layer;
};

__device__ __forceinline__ void phaseB_coop(const float* __restrict__ nv,
                                            float* __restrict__ g, float* __restrict__ dd,
                                            int bid, int tid)
{
    int gw = (bid*256 + tid) >> 6;
    int lane = tid & 63;
    #pragma unroll
    for (int r = 0; r < 5; ++r) {
        int bn = gw + r*GWAVES;
        if (bn < NB*NN) {
            int b = bn / NN;
            const float* pv = nv + (size_t)bn*NE;
            float v0=pv[0],v1=pv[1],v2=pv[2],v3=pv[3],v4=pv[4],
                  v5=pv[5],v6=pv[6],v7=pv[7],v8=pv[8],v9=pv[9];
            float sum = 0.0f;
            for (int m = lane; m < NN; m += 64) {
                const float* q = nv + ((size_t)b*NN + m)*NE;
                float dot = v0*q[0]+v1*q[1]+v2*q[2]+v3*q[3]+v4*q[4]
                          + v5*q[5]+v6*q[6]+v7*q[7]+v8*q[8]+v9*q[9];
                float gv = fmaxf(dot, 0.0f);
                g[(size_t)bn*NN + m] = gv;
                sum += gv;
            }
            #pragma unroll
            for (int off = 32; off > 0; off >>= 1) sum += __shfl_down(sum, off, 64);
            if (lane == 0) dd[bn] = 1.0f / sqrtf(sum);
        }
    }
}

__global__ __launch_bounds__(256, 2) void mg_layer_run(LP p)
{
    cg::grid_group grid = cg::this_grid();
    __shared__ alignas(16) char smraw[sizeof(SMD1)];
    const int bid = blockIdx.x, tid = threadIdx.x;

    for (int t = 0; t < NT; ++t) {
        const int c = p.layer ? (1 + (t & 1)) : 0;
        float* state = p.st + (p.layer ? (size_t)(t & 1)*NB*NN*NH : 0);
        const float* xptr = p.x + (size_t)t * p.xt;
        const float* ne0t = p.ne0 + (size_t)t * NN * NE;
        const float* wg  = p.weffg + (size_t)c*NN*2*NCIN*NO2;
        const float* bgp = p.beffg + (size_t)c*NN*NO2;
        const float* wu  = p.weffu + (size_t)c*NN*2*NCIN*NH;
        const float* bup = p.beffu + (size_t)c*NN*NH;
        const float* u1w = p.u1w + c*16*NCIN; const float* u1b = p.u1b + c*16;
        const float* u2w = p.u2w + c*2*16;    const float* u2b = p.u2b + c*2;
        const float* u3w = p.u3w + c*NE*2;    const float* u3b = p.u3b + c*NE;
        float* outi = (t >= NT-2) ? (p.outbuf + (size_t)(t-(NT-2))*NN*NH) : nullptr;

        phaseB_coop(p.nv, p.g, p.dd, bid, tid);
        grid.sync();
        for (int vb = bid; vb < NB*20; vb += GB)
            phaseC_body(p.g, p.dd, p.cat1, p.lx, smraw, vb, tid);
        grid.sync();
        for (int vb = bid; vb < 2*NN; vb += GB)
            phaseD1_body(p.cat1, p.lx, wg, bgp, state, xptr, p.xb, p.xn, ne0t,
                         u1w, u1b, u2w, u2b, u3w, u3b, p.zr, p.cat2, p.nv,
                         smraw, vb, tid);
        grid.sync();
        phaseB_coop(p.nv, p.g, p.dd, bid, tid);
        grid.sync();
        for (int vb = bid; vb < NB*20; vb += GB)
            phaseC_body(p.g, p.dd, p.cat2, p.lx, smraw, vb, tid);
        grid.sync();
        {
            bool fuse = (t < NT-1);
            int cn = p.layer ? (1 + ((t+1) & 1)) : 0;
            const float* xn   = fuse ? (p.x + (size_t)(t+1)*p.xt) : nullptr;
            const float* ne0n = fuse ? (p.ne0 + (size_t)(t+1)*NN*NE) : nullptr;
            const float* snext = p.st + (p.layer ? (size_t)((t+1)&1)*NB*NN*NH : 0);
            int same_chain = p.layer ? 0 : 1;
            for (int vb = bid; vb < 2*NN; vb += GB)
                phaseD2_body(p.cat2, p.lx, wu, bup, p.zr, state, outi,
                             same_chain, snext, xn, p.xb, p.xn, ne0n,
                             fuse ? (p.g1w + cn*16*NCIN) : nullptr, p.g1b + cn*16,
                             p.g2w + cn*2*16, p.g2b + cn*2,
                             p.g3w + cn*NE*2, p.g3b + cn*NE,
                             p.cat1, p.nv, smraw, vb, tid);
        }
        grid.sync();
    }
}

// skip conv between layers: x2 = conv(out1) + flow
__global__ void mg_conv(
    const float* __restrict__ out1, const float* __restrict__ skip_w,
    const float* __restrict__ skip_b, const float* __restrict__ src,
    float* __restrict__ x2)
{
    int idx = blockIdx.x*blockDim.x + threadIdx.x;
    if (idx >= NB*NT*NN) return;
    int n = idx % NN; int r = idx / NN; int o = r % NT; int b = r / NT;
    float acc = skip_b[o];
    #pragma unroll
    for (int c = 0; c < 2; ++c) {
        const float* p = out1 + ((size_t)(b*2+c)*NN + n)*NH;
        const float* w = skip_w + (o*2+c)*NH;
        #pragma unroll
        for (int k = 0; k < NH; ++k) acc += p[k]*w[k];
    }
    x2[idx] = acc + src[(size_t)idx*5];
}

// layernorm over concat(out1,out2) + end conv -> output
__global__ __launch_bounds__(128) void mg_final(
    const float* __restrict__ out1, const float* __restrict__ out2,
    const float* __restrict__ ln_g, const float* __restrict__ ln_b,
    const float* __restrict__ end_w, const float* __restrict__ end_b,
    float* __restrict__ dout)
{
    int bn = blockIdx.x;
    int b = bn / NN, n = bn % NN;
    int t = threadIdx.x;
    __shared__ float snorm[2][NO2];
    __shared__ float red[2];
    for (int c = 0; c < 2; ++c) {
        size_t base = ((size_t)(b*2+c)*NN + n)*NH;
        float p = (t < NH) ? out1[base + t] : out2[base + (t - NH)];
        float s = p;
        #pragma unroll
        for (int off = 32; off > 0; off >>= 1) s += __shfl_down(s, off, 64);
        if ((t & 63) == 0) red[t >> 6] = s;
        __syncthreads();
        float m = (red[0] + red[1]) * (1.0f/128.0f);
        __syncthreads();
        float df = p - m;
        float s2 = df*df;
        #pragma unroll
        for (int off = 32; off > 0; off >>= 1) s2 += __shfl_down(s2, off, 64);
        if ((t & 63) == 0) red[t >> 6] = s2;
        __syncthreads();
        float v = (red[0] + red[1]) * (1.0f/128.0f);
        snorm[c][t] = df / sqrtf(v + 1e-12f) * ln_g[t] + ln_b[t];
        __syncthreads();
    }
    if (t < NT) {
        float a = end_b[t];
        const float* w = end_w + t*2*NO2;
        for (int c = 0; c < 2; ++c)
            for (int j = 0; j < NO2; ++j)
                a += snorm[c][j] * w[c*NO2 + j];
        dout[(size_t)(b*NT + t)*NN + n] = a;
    }
}

// ---------------- host ----------------

extern "C" void kernel_launch(void* const* d_in, const int* in_sizes, int n_in,
                              void* d_out, int out_size, void* d_ws, size_t ws_size,
                              hipStream_t stream)
{
    const float* src      = (const float*)d_in[0];
    const float* node_emb = (const float*)d_in[1];
    const float* tid_emb  = (const float*)d_in[2];
    const float* dow_emb  = (const float*)d_in[3];
    const float* hol_emb  = (const float*)d_in[4];
    const float* hop_w    = (const float*)d_in[5];
    const float* hop_b    = (const float*)d_in[6];
    const float* gw  = (const float*)d_in[7];
    const float* gb  = (const float*)d_in[8];
    const float* g1w = (const float*)d_in[9];
    const float* g1b = (const float*)d_in[10];
    const float* g2w = (const float*)d_in[11];
    const float* g2b = (const float*)d_in[12];
    const float* g3w = (const float*)d_in[13];
    const float* g3b = (const float*)d_in[14];
    const float* uw  = (const float*)d_in[15];
    const float* ub  = (const float*)d_in[16];
    const float* u1w = (const float*)d_in[17];
    const float* u1b = (const float*)d_in[18];
    const float* u2w = (const float*)d_in[19];
    const float* u2b = (const float*)d_in[20];
    const float* u3w = (const float*)d_in[21];
    const float* u3b = (const float*)d_in[22];
    const float* skip_w = (const float*)d_in[23];
    const float* skip_b = (const float*)d_in[24];
    const float* ln_g = (const float*)d_in[25];
    const float* ln_b = (const float*)d_in[26];
    const float* end_w = (const float*)d_in[27];
    const float* end_b = (const float*)d_in[28];
    float* dout = (float*)d_out;

    float* ws = (float*)d_ws;
    size_t off = 0;
    float* weff_g = ws + off; off += (size_t)3*NN*2*NCIN*NO2;
    float* weff_u = ws + off; off += (size_t)3*NN*2*NCIN*NH;
    float* beff_g = ws + off; off += (size_t)3*NN*NO2;
    float* beff_u = ws + off; off += (size_t)3*NN*NH;
    float* ne0    = ws + off; off += (size_t)NB*NT*NN*NE;
    float* st     = ws + off; off += (size_t)2*NB*NN*NH;
    float* cat1   = ws + off; off += (size_t)NB*NN*NCIN;
    float* cat2   = ws + off; off += (size_t)NB*NN*NCIN;
    float* nv     = ws + off; off += (size_t)NB*NN*NE;
    float* gbuf   = ws + off; off += (size_t)NB*NN*NN;
    float* dd     = ws + off; off += (size_t)NB*NN;
    float* lx     = ws + off; off += (size_t)NB*NN*NCIN;
    float* zr     = ws + off; off += (size_t)NB*NN*NO2;
    float* out1   = ws + off; off += (size_t)NB*2*NN*NH;
    float* out2   = ws + off; off += (size_t)NB*2*NN*NH;
    float* x2     = ws + off; off += (size_t)NB*NT*NN;

    mg_ne0<<<(NB*NT*NN + 255)/256, 256, 0, stream>>>(
        src, node_emb, tid_emb, dow_emb, hol_emb, hop_w, hop_b, ne0);
    mg_weff<<<4096, 256, 0, stream>>>(
        node_emb, gw, gb, uw, ub, weff_g, beff_g, weff_u, beff_u);

    const int stcount = 2*NB*NN*NH;
    mg_zero<<<(stcount+255)/256, 256, 0, stream>>>(st, stcount);

    auto G1W = [&](int c){ return g1w + c*16*NCIN; };
    auto G1B = [&](int c){ return g1b + c*16; };
    auto G2W = [&](int c){ return g2w + c*2*16; };
    auto G2B = [&](int c){ return g2b + c*2; };
    auto G3W = [&](int c){ return g3w + c*NE*2; };
    auto G3B = [&](int c){ return g3b + c*NE; };

    // capability check for cooperative launch (environment-deterministic)
    int coopAttr = 0;
    (void)hipDeviceGetAttribute(&coopAttr, hipDeviceAttributeCooperativeLaunch, 0);
    int maxPerCU = 0;
    hipError_t qe = hipOccupancyMaxActiveBlocksPerMultiprocessor(
        &maxPerCU, (const void*)mg_layer_run, 256, 0);
    int nCU = 0;
    {
        hipDeviceProp_t props;
        if (hipGetDeviceProperties(&props, 0) == hipSuccess)
            nCU = props.multiProcessorCount;
    }
    bool coop_ok = (coopAttr != 0) && (qe == hipSuccess) && (maxPerCU * nCU >= GB);

    auto run_layer_fallback = [&](int layer, const float* x, long long xt, int xb, int xn,
                                  float* outbuf) {
        for (int t = 0; t < NT; ++t) {
            int c = layer ? (1 + (t & 1)) : 0;
            float* state = st + (layer ? (size_t)(t & 1)*NB*NN*NH : 0);
            const float* ne0t = ne0 + (size_t)t*NN*NE;
            const float* xptr = x + (size_t)t*xt;
            float* outi = (t >= NT-2) ? (outbuf + (size_t)(t-(NT-2))*NN*NH) : nullptr;
            mg_b<<<NB*NN, 64, 0, stream>>>(nv, gbuf, dd);
            mg_c<<<NB*20, 256, 0, stream>>>(gbuf, dd, cat1, lx);
            mg_d1<<<NN*2, 256, 0, stream>>>(cat1, lx,
                weff_g + (size_t)c*NN*2*NCIN*NO2, beff_g + (size_t)c*NN*NO2,
                state, xptr, xb, xn, ne0t,
                u1w + c*16*NCIN, u1b + c*16, u2w + c*2*16, u2b + c*2,
                u3w + c*NE*2, u3b + c*NE, zr, cat2, nv);
            mg_b<<<NB*NN, 64, 0, stream>>>(nv, gbuf, dd);
            mg_c<<<NB*20, 256, 0, stream>>>(gbuf, dd, cat2, lx);
            bool fuse = (t < NT-1);
            int cn = layer ? (1 + ((t+1) & 1)) : 0;
            float* chain_next = st + (layer ? (size_t)((t+1)&1)*NB*NN*NH : 0);
            const float* xnp  = fuse ? (x + (size_t)(t+1)*xt) : nullptr;
            const float* ne0n = fuse ? (ne0 + (size_t)(t+1)*NN*NE) : nullptr;
            mg_d2f<<<NN*2, 256, 0, stream>>>(cat2, lx,
                weff_u + (size_t)c*NN*2*NCIN*NH, beff_u + (size_t)c*NN*NH,
                zr, state, outi,
                layer ? 0 : 1, chain_next,
                xnp, xb, xn, ne0n,
                fuse ? G1W(cn) : nullptr, G1B(cn), G2W(cn), G2B(cn), G3W(cn), G3B(cn),
                cat1, nv);
        }
    };

    // ---- layer 1 ----
    mg_a<<<NB*NN, 64, 0, stream>>>(st, src, NT*NN*5, 5, ne0,
        G1W(0), G1B(0), G2W(0), G2B(0), G3W(0), G3B(0), cat1, nv);
    LP lp1;
    lp1.x = src; lp1.xt = NN*5; lp1.xb = NT*NN*5; lp1.xn = 5;
    lp1.ne0 = ne0;
    lp1.weffg = weff_g; lp1.beffg = beff_g; lp1.weffu = weff_u; lp1.beffu = beff_u;
    lp1.g1w = g1w; lp1.g1b = g1b; lp1.g2w = g2w; lp1.g2b = g2b;
    lp1.g3w = g3w; lp1.g3b = g3b;
    lp1.u1w = u1w; lp1.u1b = u1b; lp1.u2w = u2w; lp1.u2b = u2b;
    lp1.u3w = u3w; lp1.u3b = u3b;
    lp1.st = st; lp1.cat1 = cat1; lp1.cat2 = cat2; lp1.nv = nv; lp1.g = gbuf;
    lp1.dd = dd; lp1.lx = lx; lp1.zr = zr; lp1.outbuf = out1; lp1.layer = 0;
    bool done1 = false;
    if (coop_ok) {
        void* ka[] = { (void*)&lp1 };
        hipError_t e = hipLaunchCooperativeKernel(
            reinterpret_cast<const void*>(mg_layer_run), dim3(GB), dim3(256), ka, 0, stream);
        done1 = (e == hipSuccess);
    }
    if (!done1) run_layer_fallback(0, src, NN*5, NT*NN*5, 5, out1);

    mg_conv<<<(NB*NT*NN+255)/256, 256, 0, stream>>>(out1, skip_w, skip_b, src, x2);
    mg_zero<<<(stcount+255)/256, 256, 0, stream>>>(st, stcount);

    // ---- layer 2 ----
    mg_a<<<NB*NN, 64, 0, stream>>>(st, x2, NT*NN, 1, ne0,
        G1W(1), G1B(1), G2W(1), G2B(1), G3W(1), G3B(1), cat1, nv);
    LP lp2 = lp1;
    lp2.x = x2; lp2.xt = NN; lp2.xb = NT*NN; lp2.xn = 1;
    lp2.outbuf = out2; lp2.layer = 1;
    bool done2 = false;
    if (coop_ok) {
        void* ka[] = { (void*)&lp2 };
        hipError_t e = hipLaunchCooperativeKernel(
            reinterpret_cast<const void*>(mg_layer_run), dim3(GB), dim3(256), ka, 0, stream);
        done2 = (e == hipSuccess);
    }
    if (!done2) run_layer_fallback(1, x2, NN, NT*NN, 1, out2);

    mg_final<<<NB*NN, 128, 0, stream>>>(out1, out2, ln_g, ln_b, end_w, end_b, dout);
}